// Round 4
// baseline (121.025 us; speedup 1.0000x reference)
//
#include <hip/hip_runtime.h>

// Depthwise cross-correlation: z (64,256,7,7) over x (64,256,31,31) VALID
// -> out (64,256,25,25), scaled 0.001. fp32 end-to-end.
//
// Round 11: reg-staged pipeline (T14) -- NO global_load_lds anywhere.
//   R10 post-mortem: R7/R8/R10 all land ~37us = exact SERIAL sum of the
//   per-CU pillars (HBM 17 + DS 10 + VALU 9.3). Common factor: gl_lds.
//   Its LDS writes are vmcnt-tracked and hipcc can't prove ds_reads of the
//   buffer independent -> it inserts its own s_waitcnt vmcnt(0) before the
//   first ds_read each iteration (stricter than, and underneath, our
//   hand-placed vmcnt(14)) -> every wave drains loads AND stores every iter,
//   identical code re-phase-locks all waves -> pillars serialize.
//   Fix: stage via global_load_dwordx4 -> VGPR -> ds_write_b128. All deps are
//   register-precise: compiler emits COUNTED vmcnt for exactly the staging
//   loads (later stores never drained), and ds_write->ds_read is exact
//   lgkmcnt counting. Per-wave loop: issue next slice's 4 loads -> compute
//   current slice (~1500cy, hides ~900cy HBM latency) -> stage acc + copy
//   out -> ds_write next slice. No inline waitcnt, no barriers.
//   Grid: 2048 blocks x 2 waves x 4 slices = 16384. 8 blocks/CU, ALL
//   resident (8KB LDS/block), 16 waves/CU, zero occupancy churn.

#define KH 7
#define KW 7
#define XW 31
#define OH 25
#define OW 25
#define NSLICE (64 * 256)
#define THREADS 128
#define SPW 4                          // slices per wave
#define NBLK (NSLICE / (2 * SPW))      // 2048 blocks, exact
#define BUF_DW 1024                    // 4 KB: pre + 961 <= 964
#define SLICE_X (XW * XW)              // 961
#define SLICE_O (OH * OW)              // 625
#define X_TOTAL_DW (NSLICE * SLICE_X)  // 15,745,024

// Load one slice (961 dw + align slack) into 4x float4 regs, coalesced.
__device__ __forceinline__ void load_slice_regs(const float* __restrict__ x,
                                                int slice, int lane,
                                                float4& r0, float4& r1,
                                                float4& r2, float4& r3) {
    const int g0 = (slice * SLICE_X) & ~3;   // 16B-aligned dword base
    const int l4 = lane * 4;
    r0 = *reinterpret_cast<const float4*>(x + min(g0 + 0 * 256 + l4, X_TOTAL_DW - 4));
    r1 = *reinterpret_cast<const float4*>(x + min(g0 + 1 * 256 + l4, X_TOTAL_DW - 4));
    r2 = *reinterpret_cast<const float4*>(x + min(g0 + 2 * 256 + l4, X_TOTAL_DW - 4));
    r3 = *reinterpret_cast<const float4*>(x + min(g0 + 3 * 256 + l4, X_TOTAL_DW - 4));
}

// Write the 4 staged float4s into the wave's LDS buffer (ds_write_b128 x4).
__device__ __forceinline__ void write_slice_lds(float* __restrict__ buf, int lane,
                                                const float4& r0, const float4& r1,
                                                const float4& r2, const float4& r3) {
    const int l4 = lane * 4;
    *reinterpret_cast<float4*>(buf + 0 * 256 + l4) = r0;
    *reinterpret_cast<float4*>(buf + 1 * 256 + l4) = r1;
    *reinterpret_cast<float4*>(buf + 2 * 256 + l4) = r2;
    *reinterpret_cast<float4*>(buf + 3 * 256 + l4) = r3;
}

// Compute one slice from buf, stage scaled output into buf[0,625) (x there
// already consumed; same-wave DS ops are in-order), coalesced copy to global.
__device__ __forceinline__ void process_slice(float* __restrict__ buf,
                                              const float* __restrict__ z,
                                              float* __restrict__ out,
                                              int slice, int lane,
                                              int oy, int c0, bool act) {
    const int pre = (slice * SLICE_X) & 3;
    const float* __restrict__ zw = z + (size_t)slice * (KH * KW);
    if (act) {
        float acc[13] = {};
        const float* __restrict__ xrow = buf + pre;
        #pragma unroll
        for (int i = 0; i < KH; ++i) {
            const float* __restrict__ p = xrow + (oy + i) * XW + c0;
            float f[19];                       // h=1 reads 1 stray dw: in-bounds, unused
            #pragma unroll
            for (int c = 0; c < 19; ++c) f[c] = p[c];
            #pragma unroll
            for (int j = 0; j < KW; ++j) {
                const float w = zw[i * KW + j];   // broadcast (uniform addr)
                #pragma unroll
                for (int c = 0; c < 13; ++c)
                    acc[c] = fmaf(f[c + j], w, acc[c]);
            }
        }
        const int fb = oy * OW + c0;
        #pragma unroll
        for (int c = 0; c < 12; ++c) buf[fb + c] = acc[c] * 0.001f;
        if (c0 == 0) buf[fb + 12] = acc[12] * 0.001f;   // h=0 owns col 12
    }
    // Coalesced copy-out: 625 dwords = 9 x 64 + 49 tail -> 10 store instrs.
    float* __restrict__ og = out + (size_t)slice * SLICE_O;
    #pragma unroll
    for (int k = 0; k < 9; ++k) og[k * 64 + lane] = buf[k * 64 + lane];
    if (lane < SLICE_O - 576) og[576 + lane] = buf[576 + lane];
}

__global__ __launch_bounds__(THREADS, 4)
void xcorr_dw_kernel(const float* __restrict__ z,
                     const float* __restrict__ x,
                     float* __restrict__ out) {
    __shared__ float xs[2][BUF_DW];            // one 4 KB buffer per wave
    const int lane = threadIdx.x & 63;
    const int wv   = __builtin_amdgcn_readfirstlane(threadIdx.x >> 6);
    float* __restrict__ buf = xs[wv];

    const int wid  = blockIdx.x * 2 + wv;      // wave id in [0, 4096)
    const int base = wid * SPW;                // first slice of this wave

    // lane -> (col-half h, row oy); 50/64 lanes active in compute
    const int h   = (lane >= OH) ? 1 : 0;
    const int oy  = h ? lane - OH : lane;
    const int c0  = h ? 13 : 0;                // h=0: cols 0..12, h=1: 13..24
    const bool act = (lane < 2 * OH);

    float4 r0, r1, r2, r3;

    // Prologue: slice base -> regs -> LDS (one exposed vmcnt wait, once).
    load_slice_regs(x, base, lane, r0, r1, r2, r3);
    write_slice_lds(buf, lane, r0, r1, r2, r3);

    // Fully unrolled (SPW=4): static reg indices, uniform guards vanish.
    #pragma unroll
    for (int i = 0; i < SPW; ++i) {
        const int s = base + i;
        // Issue NEXT slice's loads before compute: they fly under ~1500cy
        // of FMA+DS work; the trailing ds_write waits only on these
        // (compiler-counted vmcnt that excludes the newer output stores).
        if (i + 1 < SPW) load_slice_regs(x, s + 1, lane, r0, r1, r2, r3);
        process_slice(buf, z, out, s, lane, oy, c0, act);
        if (i + 1 < SPW) write_slice_lds(buf, lane, r0, r1, r2, r3);
    }
}

extern "C" void kernel_launch(void* const* d_in, const int* in_sizes, int n_in,
                              void* d_out, int out_size, void* d_ws, size_t ws_size,
                              hipStream_t stream) {
    const float* z = (const float*)d_in[0];   // (64,256,7,7)
    const float* x = (const float*)d_in[1];   // (64,256,31,31)
    float* out = (float*)d_out;               // (64,256,25,25)
    xcorr_dw_kernel<<<dim3(NBLK), dim3(THREADS), 0, stream>>>(z, x, out);
}

// Round 5
// 116.833 us; speedup vs baseline: 1.0359x; 1.0359x over previous
//
#include <hip/hip_runtime.h>

// Depthwise cross-correlation: z (64,256,7,7) over x (64,256,31,31) VALID
// -> out (64,256,25,25), scaled 0.001. fp32 end-to-end.
//
// Round 12: producer/consumer wave specialization (T16).
//   History: every homogeneous-wave schedule (R7 block-phase, R8 wave-
//   autonomous, R10 persistent dbuf+counted-vmcnt) = 37-42us = EXACT serial
//   sum of per-CU pillars (HBM 17us + DS ~9.5us + VALU 9.3us). Identical
//   per-wave code re-phase-locks via shared-pipe backpressure, so pillars
//   never overlap. R11 (reg-staged) spilled (WRITE_SIZE 41->54.8MB) -> 60us.
//   Fix: give each pillar its own WAVE CLASS. 256-thr blocks = 3 consumer
//   waves + 1 producer wave; 1536 blocks = 6/CU, 24KB LDS, fully resident.
//   Producer: stages 3 contiguous slices/round (12 x gl_lds, 12KB) into the
//   idle half of a double buffer, then vmcnt(0) IN ITS OWN WAVE -> all HBM
//   latency lives in a wave with nothing else to do. Consumers: compute one
//   slice each per round with ZERO vmcnt waits (stores fire-and-forget,
//   z via s_load/lgkm). gl_lds alias-poison can't reach consumers: they
//   issue no gl_lds, and the producer path exits each round at vmcnt=0.
//   Raw s_barrier per round (no __syncthreads -> no forced store drain).
//   Hazards: producer vmcnt(0)+barrier publishes x; consumer out-stage
//   ds_writes are read back same-wave before stores -> retired pre-barrier;
//   producer always targets the opposite buffer half.

#define KH 7
#define KW 7
#define XW 31
#define OH 25
#define OW 25
#define NSLICE (64 * 256)
#define THREADS 256
#define NBLK 1536                      // 6 blocks/CU x 256 CU, all resident
#define RND 4                          // rounds: 1536*3*4 = 18432 >= 16384
#define HALF_DW 3072                   // 3 slices (2883 dw) + align slack
#define SLICE_X (XW * XW)              // 961
#define SLICE_O (OH * OW)              // 625
#define X_TOTAL_DW (NSLICE * SLICE_X)  // 15,745,024

__device__ __forceinline__ void gl_lds16(const float* g, float* l) {
    __builtin_amdgcn_global_load_lds(
        (const __attribute__((address_space(1))) void*)g,
        (__attribute__((address_space(3))) void*)l, 16, 0, 0);
}

// Producer: stage 3 contiguous slices (2883 dw + slack) = 12 x (64 x 16 B).
__device__ __forceinline__ void stage3(const float* __restrict__ x,
                                       float* __restrict__ half,
                                       int sbase, int lane) {
    const int g0 = (sbase * SLICE_X) & ~3;     // 16B-aligned; slack in [0,3]
    #pragma unroll
    for (int k = 0; k < 12; ++k) {
        const int dw = k * 256 + lane * 4;
        gl_lds16(x + min(g0 + dw, X_TOTAL_DW - 4), half + dw);  // clamp: tail/idle
    }
}

__global__ __launch_bounds__(THREADS, 6)
void xcorr_dw_kernel(const float* __restrict__ z,
                     const float* __restrict__ x,
                     float* __restrict__ out) {
    __shared__ float xs[2][HALF_DW];           // 24 KB double buffer
    const int lane = threadIdx.x & 63;
    const int wv   = __builtin_amdgcn_readfirstlane(threadIdx.x >> 6);
    const int b    = blockIdx.x;               // block owns slices [12b, 12b+12)

    if (wv == 3) {
        // ---------------- producer wave ----------------
        stage3(x, xs[0], 12 * b, lane);
        asm volatile("s_waitcnt vmcnt(0)" ::: "memory");
        __builtin_amdgcn_sched_barrier(0);
        #pragma unroll 1
        for (int r = 0; r < RND; ++r) {
            __builtin_amdgcn_s_barrier();      // B_r: round r data published
            if (r + 1 < RND) {
                // Fill the half consumers just vacated (round r-1's buffer).
                stage3(x, xs[(r + 1) & 1], 12 * b + 3 * (r + 1), lane);
                asm volatile("s_waitcnt vmcnt(0)" ::: "memory");
                __builtin_amdgcn_sched_barrier(0);
            }
        }
    } else {
        // ---------------- consumer waves (wv = 0,1,2) ----------------
        const int h   = (lane >= OH) ? 1 : 0;
        const int oy  = h ? lane - OH : lane;
        const int c0  = h ? 13 : 0;            // h=0: cols 0..12, h=1: 13..24
        const bool act = (lane < 2 * OH);
        #pragma unroll 1
        for (int r = 0; r < RND; ++r) {
            __builtin_amdgcn_s_barrier();      // wait for producer's round r
            const int sbase = 12 * b + 3 * r;
            const int s     = sbase + wv;
            if (s < NSLICE) {
                const int pre = (sbase * SLICE_X) & 3;
                float* __restrict__ buf = xs[r & 1] + pre + wv * SLICE_X;
                const float* __restrict__ zw = z + (size_t)s * (KH * KW);
                if (act) {
                    float acc[13] = {};
                    #pragma unroll
                    for (int i = 0; i < KH; ++i) {
                        const float* __restrict__ p = buf + (oy + i) * XW + c0;
                        float f[19];           // h=1's f[18] lands in next slice's
                        #pragma unroll         // first dw: in-LDS-bounds, discarded
                        for (int c = 0; c < 19; ++c) f[c] = p[c];
                        #pragma unroll
                        for (int j = 0; j < KW; ++j) {
                            const float w = zw[i * KW + j];   // uniform s_load
                            #pragma unroll
                            for (int c = 0; c < 13; ++c)
                                acc[c] = fmaf(f[c + j], w, acc[c]);
                        }
                    }
                    // Out-stage into own consumed x region [0,625) of buf.
                    const int fb = oy * OW + c0;
                    #pragma unroll
                    for (int c = 0; c < 12; ++c) buf[fb + c] = acc[c] * 0.001f;
                    if (c0 == 0) buf[fb + 12] = acc[12] * 0.001f;
                }
                // Coalesced copy-out: 625 dw = 9 x 64 + 49 tail.
                float* __restrict__ og = out + (size_t)s * SLICE_O;
                #pragma unroll
                for (int k = 0; k < 9; ++k) og[k * 64 + lane] = buf[k * 64 + lane];
                if (lane < SLICE_O - 576) og[576 + lane] = buf[576 + lane];
            }
        }
    }
}

extern "C" void kernel_launch(void* const* d_in, const int* in_sizes, int n_in,
                              void* d_out, int out_size, void* d_ws, size_t ws_size,
                              hipStream_t stream) {
    const float* z = (const float*)d_in[0];   // (64,256,7,7)
    const float* x = (const float*)d_in[1];   // (64,256,31,31)
    float* out = (float*)d_out;               // (64,256,25,25)
    xcorr_dw_kernel<<<dim3(NBLK), dim3(THREADS), 0, stream>>>(z, x, out);
}